// Round 1
// baseline (94.553 us; speedup 1.0000x reference)
//
#include <hip/hip_runtime.h>

// Problem constants (from reference):
// input x: (B=256, T=600, J=25, C=3, 1) float32
// viewed as (B, NP=5, P=5, T, C) with x[b,n,p,t,c] = in[((b*600+t)*25 + n*5+p)*3 + c]
// output: (B, 5, 1800, 4, 4) float32; windows (start,len,out_off):
//   (0,600,0) (0,300,600) (300,300,900) (0,200,1200) (200,200,1400) (400,200,1600)

#define B_ 256
#define T_ 600
#define TOUT_ 1800
#define TOTAL_ (B_ * 5 * TOUT_)

__global__ __launch_bounds__(256) void gauss_agg_kernel(const float* __restrict__ x,
                                                        float* __restrict__ out) {
    int gid = blockIdx.x * blockDim.x + threadIdx.x;
    if (gid >= TOTAL_) return;

    int tout = gid % TOUT_;
    int bn   = gid / TOUT_;   // b*5 + n
    int b = bn / 5;
    int n = bn - 5 * b;

    // window decode: rel = index within window, tt = global time, Lw = window len
    int rel, tt, Lw;
    if (tout < 600)       { rel = tout;        tt = rel;       Lw = 600; }
    else if (tout < 900)  { rel = tout - 600;  tt = rel;       Lw = 300; }
    else if (tout < 1200) { rel = tout - 900;  tt = 300 + rel; Lw = 300; }
    else if (tout < 1400) { rel = tout - 1200; tt = rel;       Lw = 200; }
    else if (tout < 1600) { rel = tout - 1400; tt = 200 + rel; Lw = 200; }
    else                  { rel = tout - 1600; tt = 400 + rel; Lw = 200; }
    bool boundary = (rel == 0) || (rel == Lw - 1);

    const float* p0 = x + ((size_t)b * T_ + tt) * 75 + n * 15;

    float s0 = 0.f, s1 = 0.f, s2 = 0.f;
    float A00 = 0.f, A01 = 0.f, A02 = 0.f, A11 = 0.f, A12 = 0.f, A22 = 0.f;
    float m0 = 0.f, m1 = 0.f, m2 = 0.f;

    // center time: accumulate plain sum, outer-product sum, and smoothed-mean (mu)
    {
        const float w[5] = {4.f, 2.f, 3.f, 2.f, 4.f};
        #pragma unroll
        for (int p = 0; p < 5; ++p) {
            float a = p0[p * 3 + 0];
            float c = p0[p * 3 + 1];
            float d = p0[p * 3 + 2];
            s0 += a; s1 += c; s2 += d;
            m0 += w[p] * a; m1 += w[p] * c; m2 += w[p] * d;
            A00 += a * a; A01 += a * c; A02 += a * d;
            A11 += c * c; A12 += c * d; A22 += d * d;
        }
    }
    float mu0 = m0 * (1.f / 15.f);
    float mu1 = m1 * (1.f / 15.f);
    float mu2 = m2 * (1.f / 15.f);

    float inv = 1.f / 5.f;
    if (!boundary) {
        #pragma unroll
        for (int dstep = 0; dstep < 2; ++dstep) {
            const float* pn = p0 + (dstep ? 75 : -75);
            #pragma unroll
            for (int p = 0; p < 5; ++p) {
                float a = pn[p * 3 + 0];
                float c = pn[p * 3 + 1];
                float d = pn[p * 3 + 2];
                s0 += a; s1 += c; s2 += d;
                A00 += a * a; A01 += a * c; A02 += a * d;
                A11 += c * c; A12 += c * d; A22 += d * d;
            }
        }
        inv = 1.f / 15.f;
    }

    // mb = mean over (5*k) samples; Ab = second-moment sum / (5*k)
    float mb0 = s0 * inv, mb1 = s1 * inv, mb2 = s2 * inv;
    float e00 = A00 * inv - 2.f * mu0 * mb0 + 2.f * mu0 * mu0;
    float e01 = A01 * inv - mu0 * mb1 - mb0 * mu1 + 2.f * mu0 * mu1;
    float e02 = A02 * inv - mu0 * mb2 - mb0 * mu2 + 2.f * mu0 * mu2;
    float e11 = A11 * inv - 2.f * mu1 * mb1 + 2.f * mu1 * mu1;
    float e12 = A12 * inv - mu1 * mb2 - mb1 * mu2 + 2.f * mu1 * mu2;
    float e22 = A22 * inv - 2.f * mu2 * mb2 + 2.f * mu2 * mu2;

    float4* op = reinterpret_cast<float4*>(out) + (size_t)gid * 4;
    op[0] = make_float4(e00, e01, e02, mu0);
    op[1] = make_float4(e01, e11, e12, mu1);
    op[2] = make_float4(e02, e12, e22, mu2);
    op[3] = make_float4(mu0, mu1, mu2, 1.f);
}

extern "C" void kernel_launch(void* const* d_in, const int* in_sizes, int n_in,
                              void* d_out, int out_size, void* d_ws, size_t ws_size,
                              hipStream_t stream) {
    const float* x = (const float*)d_in[0];
    float* out = (float*)d_out;
    int blocks = (TOTAL_ + 255) / 256;
    gauss_agg_kernel<<<blocks, 256, 0, stream>>>(x, out);
}

// Round 2
// 75.928 us; speedup vs baseline: 1.2453x; 1.2453x over previous
//
#include <hip/hip_runtime.h>

// input x: (B=256, T=600, J=25, C=3) f32; x[b,t,n*5+p,c] = in[(b*600+t)*75 + n*15 + p*3 + c]
// output: (B, 5, 1800, 4, 4) f32.
// For global time tt, the 3 windows' outputs sit at tout = tt, 600+tt, 1200+tt.
// Interior result (3-time cov, mu(tt)) is identical across windows; only
// window-boundary slots use the center-only (5-sample) form.

#define B_ 256
#define T_ 600
#define TILE_ 50          // tt per block; 5 n-groups * 50 = 250 active threads
#define TILES_PER_B 12    // 600 / 50

__global__ __launch_bounds__(256) void gauss_agg_kernel(const float* __restrict__ x,
                                                        float* __restrict__ out) {
    int blk = blockIdx.x;
    int b    = blk / TILES_PER_B;
    int tile = blk - b * TILES_PER_B;
    int tid = threadIdx.x;
    if (tid >= 5 * TILE_) return;
    int n  = tid / TILE_;
    int tl = tid - n * TILE_;
    int tt = tile * TILE_ + tl;

    const float* p0 = x + ((size_t)b * T_ + tt) * 75 + n * 15;

    // ---- center time: plain sum, outer-product sum, weighted (smoothed) mean ----
    float s0 = 0.f, s1 = 0.f, s2 = 0.f;
    float A00 = 0.f, A01 = 0.f, A02 = 0.f, A11 = 0.f, A12 = 0.f, A22 = 0.f;
    float m0 = 0.f, m1 = 0.f, m2 = 0.f;
    const float w5[5] = {4.f, 2.f, 3.f, 2.f, 4.f};
    #pragma unroll
    for (int p = 0; p < 5; ++p) {
        float a = p0[p * 3 + 0];
        float c = p0[p * 3 + 1];
        float d = p0[p * 3 + 2];
        s0 += a; s1 += c; s2 += d;
        m0 += w5[p] * a; m1 += w5[p] * c; m2 += w5[p] * d;
        A00 += a * a; A01 += a * c; A02 += a * d;
        A11 += c * c; A12 += c * d; A22 += d * d;
    }
    float mu0 = m0 * (1.f / 15.f);
    float mu1 = m1 * (1.f / 15.f);
    float mu2 = m2 * (1.f / 15.f);

    // snapshot center-only sums (for window-boundary slots)
    float cs0 = s0, cs1 = s1, cs2 = s2;
    float cA00 = A00, cA01 = A01, cA02 = A02, cA11 = A11, cA12 = A12, cA22 = A22;

    bool edge = (tt == 0) || (tt == T_ - 1);
    if (!edge) {
        #pragma unroll
        for (int dstep = 0; dstep < 2; ++dstep) {
            const float* pn = p0 + (dstep ? 75 : -75);
            #pragma unroll
            for (int p = 0; p < 5; ++p) {
                float a = pn[p * 3 + 0];
                float c = pn[p * 3 + 1];
                float d = pn[p * 3 + 2];
                s0 += a; s1 += c; s2 += d;
                A00 += a * a; A01 += a * c; A02 += a * d;
                A11 += c * c; A12 += c * d; A22 += d * d;
            }
        }
    }

    // center-only (boundary) moments: inv = 1/5
    float mb0 = cs0 * 0.2f, mb1 = cs1 * 0.2f, mb2 = cs2 * 0.2f;
    float eC00 = cA00 * 0.2f - 2.f * mu0 * mb0 + 2.f * mu0 * mu0;
    float eC01 = cA01 * 0.2f - mu0 * mb1 - mb0 * mu1 + 2.f * mu0 * mu1;
    float eC02 = cA02 * 0.2f - mu0 * mb2 - mb0 * mu2 + 2.f * mu0 * mu2;
    float eC11 = cA11 * 0.2f - 2.f * mu1 * mb1 + 2.f * mu1 * mu1;
    float eC12 = cA12 * 0.2f - mu1 * mb2 - mb1 * mu2 + 2.f * mu1 * mu2;
    float eC22 = cA22 * 0.2f - 2.f * mu2 * mb2 + 2.f * mu2 * mu2;

    // interior (3-time) moments: inv = 1/15  (garbage at edge tt, never stored there)
    const float invI = 1.f / 15.f;
    float mi0 = s0 * invI, mi1 = s1 * invI, mi2 = s2 * invI;
    float eI00 = A00 * invI - 2.f * mu0 * mi0 + 2.f * mu0 * mu0;
    float eI01 = A01 * invI - mu0 * mi1 - mi0 * mu1 + 2.f * mu0 * mu1;
    float eI02 = A02 * invI - mu0 * mi2 - mi0 * mu2 + 2.f * mu0 * mu2;
    float eI11 = A11 * invI - 2.f * mu1 * mi1 + 2.f * mu1 * mu1;
    float eI12 = A12 * invI - mu1 * mi2 - mi1 * mu2 + 2.f * mu1 * mu2;
    float eI22 = A22 * invI - 2.f * mu2 * mi2 + 2.f * mu2 * mu2;

    float4 rI0 = make_float4(eI00, eI01, eI02, mu0);
    float4 rI1 = make_float4(eI01, eI11, eI12, mu1);
    float4 rI2 = make_float4(eI02, eI12, eI22, mu2);
    float4 rC0 = make_float4(eC00, eC01, eC02, mu0);
    float4 rC1 = make_float4(eC01, eC11, eC12, mu1);
    float4 rC2 = make_float4(eC02, eC12, eC22, mu2);
    float4 r3  = make_float4(mu0, mu1, mu2, 1.f);

    // window boundary masks
    bool bd0 = edge;
    bool bd1 = edge || (tt == 299) || (tt == 300);
    bool bd2 = edge || (tt == 199) || (tt == 200) || (tt == 399) || (tt == 400);

    float4* obase = reinterpret_cast<float4*>(out) + ((size_t)(b * 5 + n) * 1800 + tt) * 4;
    // window 0 at tout = tt
    { float4* op = obase;
      op[0] = bd0 ? rC0 : rI0; op[1] = bd0 ? rC1 : rI1; op[2] = bd0 ? rC2 : rI2; op[3] = r3; }
    // window 1 at tout = 600 + tt
    { float4* op = obase + 600 * 4;
      op[0] = bd1 ? rC0 : rI0; op[1] = bd1 ? rC1 : rI1; op[2] = bd1 ? rC2 : rI2; op[3] = r3; }
    // window 2 at tout = 1200 + tt
    { float4* op = obase + 1200 * 4;
      op[0] = bd2 ? rC0 : rI0; op[1] = bd2 ? rC1 : rI1; op[2] = bd2 ? rC2 : rI2; op[3] = r3; }
}

extern "C" void kernel_launch(void* const* d_in, const int* in_sizes, int n_in,
                              void* d_out, int out_size, void* d_ws, size_t ws_size,
                              hipStream_t stream) {
    const float* x = (const float*)d_in[0];
    float* out = (float*)d_out;
    int blocks = B_ * TILES_PER_B;   // 3072 blocks, 256 threads (250 active)
    gauss_agg_kernel<<<blocks, 256, 0, stream>>>(x, out);
}